// Round 22
// baseline (194.701 us; speedup 1.0000x reference)
//
#include <hip/hip_runtime.h>
#include <hip/hip_bf16.h>
#include <cstdint>

typedef uint16_t u16;
typedef __attribute__((ext_vector_type(8))) __bf16 bf16x8;
typedef __attribute__((ext_vector_type(4))) float f32x4;
typedef __attribute__((ext_vector_type(16))) float f32x16;
typedef __attribute__((ext_vector_type(8))) unsigned short u16x8;

#define GLD_LDS(SRC, DST) \
  __builtin_amdgcn_global_load_lds((const __attribute__((address_space(1))) void*)(SRC), \
                                   (__attribute__((address_space(3))) void*)(DST), 16, 0, 0)

// v_permlane32_swap_b32 d, s: new_d = {d.lo31, s.lo31}, new_s = {d.hi31, s.hi31}
#define PSWAP(d, s) asm volatile("v_permlane32_swap_b32 %0, %1" : "+v"(d), "+v"(s))

__device__ __forceinline__ u16 f2bf(float f) {
  uint32_t u = __float_as_uint(f);
  u += 0x7fffu + ((u >> 16) & 1u);   // RNE; inputs are finite
  return (u16)(u >> 16);
}

__device__ __forceinline__ float bf2f(u16 u) {
  return __uint_as_float(((uint32_t)u) << 16);
}

__device__ __forceinline__ uint32_t pk2(float a, float b) {
  union { __bf16 h[2]; uint32_t u; } x;
  x.h[0] = (__bf16)a; x.h[1] = (__bf16)b;
  return x.u;
}

__device__ __forceinline__ float fexp2(float x) {
#if __has_builtin(__builtin_amdgcn_exp2f)
  return __builtin_amdgcn_exp2f(x);
#else
  return exp2f(x);
#endif
}

// ---------------- fused prep: cast x, transpose Wq/Wk/Wv/Wo, rope tables ----------------
__global__ __launch_bounds__(256) void prep_all(const float* __restrict__ x, u16* __restrict__ Xb,
    const float* __restrict__ Wq, const float* __restrict__ Wk, const float* __restrict__ Wv,
    const float* __restrict__ Wo, u16* __restrict__ Wcat, u16* __restrict__ WoT,
    float* __restrict__ cosT, float* __restrict__ sinT) {
  int bid = blockIdx.x, tid = threadIdx.x;
  if (bid < 2048) {                     // cast: 4 float4 / thread
    int base = bid * 1024 + tid;
    #pragma unroll
    for (int k = 0; k < 4; ++k) {
      int i = base + k * 256;
      float4 v = reinterpret_cast<const float4*>(x)[i];
      ushort4 o;
      o.x = f2bf(v.x); o.y = f2bf(v.y); o.z = f2bf(v.z); o.w = f2bf(v.w);
      reinterpret_cast<ushort4*>(Xb)[i] = o;
    }
    return;
  }
  if (bid >= 8192 && bid < 8448) {      // rope tables: 8 t per block
    int b2 = bid - 8192;
    int t = b2 * 8 + (tid >> 5), i = tid & 31;
    float invf = powf(10000.0f, -(float)i * (1.0f / 32.0f));
    float ang = (float)t * invf;
    cosT[t * 32 + i] = cosf(ang);
    sinT[t * 32 + i] = sinf(ang);
    return;
  }
  __shared__ float tile[32][33];
  const float* W; u16* Wt; int N, bx, by;
  if (bid < 6144)      { int b2 = bid - 2048; W = Wq; Wt = Wcat;               N = 2048; bx = b2 & 63; by = b2 >> 6; }
  else if (bid < 7168) { int b2 = bid - 6144; W = Wk; Wt = Wcat + 2048 * 2048; N = 512;  bx = b2 & 15; by = b2 >> 4; }
  else if (bid < 8192) { int b2 = bid - 7168; W = Wv; Wt = Wcat + 2560 * 2048; N = 512;  bx = b2 & 15; by = b2 >> 4; }
  else                 { int b2 = bid - 8448; W = Wo; Wt = WoT;                N = 2048; bx = b2 & 63; by = b2 >> 6; }
  int n0 = bx * 32, k0 = by * 32;
  int tx = tid & 31, ty = tid >> 5;
  #pragma unroll
  for (int i = ty; i < 32; i += 8)
    tile[i][tx] = W[(size_t)(k0 + i) * N + n0 + tx];
  __syncthreads();
  #pragma unroll
  for (int i = ty; i < 32; i += 8)
    Wt[(size_t)(n0 + i) * 2048 + k0 + tx] = f2bf(tile[tx][i]);
}

// ---------------- QKV GEMM: 256^2 tile, paired-phase (R14-proven core) ----------------
// V epilogue (blocks bx>=10): LDS-transpose (reusing staging LDS) -> coalesced Vtr
// bf16 writes ONLY (outV handled by v_upcast). Other blocks write Cq.
__global__ __launch_bounds__(512, 2) void gemm_qkv(const u16* __restrict__ A,
    const u16* __restrict__ Bt, u16* __restrict__ Cq, u16* __restrict__ Vtr) {
  __shared__ alignas(16) u16 Asm[2][2][256][32];   // 64 KB
  __shared__ alignas(16) u16 Bsm[2][2][256][32];   // 64 KB

  const int K = 2048, N = 3072;
  const int tid = threadIdx.x;
  const int l = tid & 63;
  const int w = tid >> 6;
  const int wm = w >> 2, wn = w & 3;
  const int l15 = l & 15, l4 = l >> 4;
  const int m0 = blockIdx.y * 256, n0 = blockIdx.x * 256;
  const int NT = K >> 6;               // 32

  f32x4 acc[8][4] = {};

  const int srow = tid >> 2;
  const int sg   = (tid & 3) ^ ((srow >> 1) & 3);
  const u16* Ag = A + (size_t)(m0 + srow) * K + sg * 8;
  const u16* Bg = Bt + (size_t)(n0 + srow) * K + sg * 8;
  const size_t rsk = (size_t)128 * K;
  char* AsD = (char*)&Asm[0][0][0][0] + tid * 16;
  char* BsD = (char*)&Bsm[0][0][0][0] + tid * 16;

#define STAGE_A(BUF, KH, KT) do { \
    GLD_LDS(Ag + (KT) + (KH) * 32,       AsD + ((BUF) * 2 + (KH)) * 16384); \
    GLD_LDS(Ag + (KT) + (KH) * 32 + rsk, AsD + ((BUF) * 2 + (KH)) * 16384 + 8192); \
  } while (0)
#define STAGE_B(BUF, KH, KT) do { \
    GLD_LDS(Bg + (KT) + (KH) * 32,       BsD + ((BUF) * 2 + (KH)) * 16384); \
    GLD_LDS(Bg + (KT) + (KH) * 32 + rsk, BsD + ((BUF) * 2 + (KH)) * 16384 + 8192); \
  } while (0)

  STAGE_A(0, 0, 0);  STAGE_B(0, 0, 0);
  STAGE_A(0, 1, 0);  STAGE_B(0, 1, 0);
  STAGE_A(1, 0, 64); STAGE_B(1, 0, 64);   // 12 outstanding

  const int swz = (l15 >> 1) & 3;

  for (int t = 0; t < NT; ++t) {
    const int c = t & 1;
    const int ktn  = (t + 1) << 6;
    const int ktn2 = (t + 2) << 6;
    bf16x8 bfv[4], af0[4], af1[4];

    // ---------- Phase A: kh=0, both mh halves ----------
    if (t < NT - 1) { asm volatile("s_waitcnt vmcnt(8)" ::: "memory"); }
    else            { asm volatile("s_waitcnt vmcnt(4)" ::: "memory"); }
    asm volatile("s_barrier" ::: "memory");
    #pragma unroll
    for (int nf = 0; nf < 4; ++nf)
      bfv[nf] = *(const bf16x8*)&Bsm[c][0][wn * 64 + nf * 16 + l15][(l4 ^ swz) * 8];
    #pragma unroll
    for (int mf = 0; mf < 4; ++mf)
      af0[mf] = *(const bf16x8*)&Asm[c][0][wm * 128 + mf * 16 + l15][(l4 ^ swz) * 8];
    if (t + 1 < NT) STAGE_A(c ^ 1, 1, ktn);
    #pragma unroll
    for (int mf = 0; mf < 4; ++mf)     // issued early; land under p0 MFMAs
      af1[mf] = *(const bf16x8*)&Asm[c][0][wm * 128 + 64 + mf * 16 + l15][(l4 ^ swz) * 8];
    __builtin_amdgcn_s_setprio(1);
    #pragma unroll
    for (int mf = 0; mf < 4; ++mf)
      #pragma unroll
      for (int nf = 0; nf < 4; ++nf)
        acc[mf][nf] = __builtin_amdgcn_mfma_f32_16x16x32_bf16(af0[mf], bfv[nf], acc[mf][nf], 0, 0, 0);
    __builtin_amdgcn_s_setprio(0);
    if (t + 1 < NT) STAGE_B(c ^ 1, 1, ktn);
    __builtin_amdgcn_s_setprio(1);
    #pragma unroll
    for (int mf = 0; mf < 4; ++mf)
      #pragma unroll
      for (int nf = 0; nf < 4; ++nf)
        acc[4 + mf][nf] = __builtin_amdgcn_mfma_f32_16x16x32_bf16(af1[mf], bfv[nf], acc[4 + mf][nf], 0, 0, 0);
    __builtin_amdgcn_s_setprio(0);
    asm volatile("s_barrier" ::: "memory");

    // ---------- Phase B: kh=1, both mh halves ----------
    if (t < NT - 1) { asm volatile("s_waitcnt vmcnt(8)" ::: "memory"); }
    else            { asm volatile("s_waitcnt vmcnt(0)" ::: "memory"); }
    asm volatile("s_barrier" ::: "memory");
    #pragma unroll
    for (int nf = 0; nf < 4; ++nf)
      bfv[nf] = *(const bf16x8*)&Bsm[c][1][wn * 64 + nf * 16 + l15][(l4 ^ swz) * 8];
    #pragma unroll
    for (int mf = 0; mf < 4; ++mf)
      af0[mf] = *(const bf16x8*)&Asm[c][1][wm * 128 + mf * 16 + l15][(l4 ^ swz) * 8];
    if (t + 2 < NT) STAGE_A(c, 0, ktn2);
    #pragma unroll
    for (int mf = 0; mf < 4; ++mf)
      af1[mf] = *(const bf16x8*)&Asm[c][1][wm * 128 + 64 + mf * 16 + l15][(l4 ^ swz) * 8];
    __builtin_amdgcn_s_setprio(1);
    #pragma unroll
    for (int mf = 0; mf < 4; ++mf)
      #pragma unroll
      for (int nf = 0; nf < 4; ++nf)
        acc[mf][nf] = __builtin_amdgcn_mfma_f32_16x16x32_bf16(af0[mf], bfv[nf], acc[mf][nf], 0, 0, 0);
    __builtin_amdgcn_s_setprio(0);
    if (t + 2 < NT) STAGE_B(c, 0, ktn2);
    __builtin_amdgcn_s_setprio(1);
    #pragma unroll
    for (int mf = 0; mf < 4; ++mf)
      #pragma unroll
      for (int nf = 0; nf < 4; ++nf)
        acc[4 + mf][nf] = __builtin_amdgcn_mfma_f32_16x16x32_bf16(af1[mf], bfv[nf], acc[4 + mf][nf], 0, 0, 0);
    __builtin_amdgcn_s_setprio(0);
    asm volatile("s_barrier" ::: "memory");
  }
#undef STAGE_A
#undef STAGE_B

  if (blockIdx.x >= 10) {
    // ---- V epilogue: transpose through (dead) staging LDS, then coalesced Vtr stores ----
    const int b   = m0 >> 11;
    const int tb  = m0 & 2047;                 // t base of this block
    const int gvb = (blockIdx.x - 10) * 4;     // kv-group base (bx=10 -> 0, bx=11 -> 4)
    char* ldsA = (char*)&Asm[0][0][0][0];      // c2 <  128 : 64 KB, pitch 512 B
    char* ldsB = (char*)&Bsm[0][0][0][0];      // c2 >= 128 : 64 KB
    #pragma unroll
    for (int mi = 0; mi < 8; ++mi)
      #pragma unroll
      for (int nf = 0; nf < 4; ++nf) {
        int c2 = wn * 64 + nf * 16 + l15;      // 0..255 (uniform array select per wave)
        int tloc = wm * 128 + mi * 16 + l4 * 4;
        char* base = (c2 & 128) ? ldsB : ldsA;
        uint32_t byte = (uint32_t)(c2 & 127) * 512 +
                        (((uint32_t)tloc * 2) ^ ((uint32_t)(c2 & 7) << 4));
        union { uint32_t w2[2]; uint64_t q; } pq;
        pq.w2[0] = pk2(acc[mi][nf][0], acc[mi][nf][1]);
        pq.w2[1] = pk2(acc[mi][nf][2], acc[mi][nf][3]);
        *reinterpret_cast<uint64_t*>(base + byte) = pq.q;
      }
    __syncthreads();
    #pragma unroll
    for (int it = 0; it < 16; ++it) {
      int chunk = tid + it * 512;              // 0..8191
      int c2 = chunk >> 5;
      int tc = chunk & 31;
      char* base = (c2 & 128) ? ldsB : ldsA;
      uint32_t byte = (uint32_t)(c2 & 127) * 512 +
                      (((uint32_t)tc * 16) ^ ((uint32_t)(c2 & 7) << 4));
      bf16x8 v = *reinterpret_cast<const bf16x8*>(base + byte);
      int gv = c2 >> 6, d = c2 & 63;
      u16* vt = Vtr + (size_t)(b * 8 + gvb + gv) * 64 * 2048 + (size_t)d * 2048 + tb + tc * 8;
      *reinterpret_cast<bf16x8*>(vt) = v;
    }
  } else {
    #pragma unroll
    for (int mi = 0; mi < 8; ++mi)
      #pragma unroll
      for (int nf = 0; nf < 4; ++nf)
        #pragma unroll
        for (int r = 0; r < 4; ++r) {
          int row = m0 + wm * 128 + mi * 16 + l4 * 4 + r;
          int col = n0 + wn * 64 + nf * 16 + l15;
          Cq[(size_t)row * N + col] = f2bf(acc[mi][nf][r]);
        }
  }
}

// ---------------- v_upcast: Vtr bf16 [bg][64 d][2048 t] -> outV fp32 [bg][2048 t][64 d] ----------------
__global__ __launch_bounds__(256) void v_upcast(const u16* __restrict__ Vtr, float* __restrict__ outV) {
  __shared__ u16 tile[64][72];   // pitch 72 (16B-aligned rows)
  int tt = blockIdx.x, bg = blockIdx.y;
  int tid = threadIdx.x;
  const u16* sp = Vtr + (size_t)bg * 64 * 2048 + tt * 64;
  int d = tid >> 2, j0 = (tid & 3) * 16;
  *(bf16x8*)&tile[d][j0]     = *(const bf16x8*)(sp + (size_t)d * 2048 + j0);
  *(bf16x8*)&tile[d][j0 + 8] = *(const bf16x8*)(sp + (size_t)d * 2048 + j0 + 8);
  __syncthreads();
  int t = tid >> 2, c0 = (tid & 3) * 16;
  float* op = outV + ((size_t)bg * 2048 + tt * 64 + t) * 64 + c0;
  #pragma unroll
  for (int i = 0; i < 16; i += 4) {
    float4 v;
    v.x = bf2f(tile[c0 + i + 0][t]);
    v.y = bf2f(tile[c0 + i + 1][t]);
    v.z = bf2f(tile[c0 + i + 2][t]);
    v.w = bf2f(tile[c0 + i + 3][t]);
    *reinterpret_cast<float4*>(op + i) = v;
  }
}

// ---------------- 128x256-tile GEMM (f32 out), split-phase (R14-proven) ----------------
__global__ __launch_bounds__(512, 2) void gemm128(const u16* __restrict__ A,
    const u16* __restrict__ Bt, float* __restrict__ C, int M, int N, int K) {
  __shared__ alignas(16) u16 Asm[2][2][128][32];   // 32 KB
  __shared__ alignas(16) u16 Bsm[2][2][256][32];   // 64 KB

  const int tid = threadIdx.x;
  const int l = tid & 63;
  const int w = tid >> 6;
  const int wm = w >> 2, wn = w & 3;
  const int l15 = l & 15, l4 = l >> 4;
  const int m0 = blockIdx.y * 128, n0 = blockIdx.x * 256;
  const int NT = K >> 6;

  f32x4 acc[4][4] = {};

  const int srow = tid >> 2;
  const int sg   = (tid & 3) ^ ((srow >> 1) & 3);
  const u16* Ag = A + (size_t)(m0 + srow) * K + sg * 8;
  const u16* Bg = Bt + (size_t)(n0 + srow) * K + sg * 8;
  const size_t rsk = (size_t)128 * K;
  char* AsD = (char*)&Asm[0][0][0][0] + tid * 16;
  char* BsD = (char*)&Bsm[0][0][0][0] + tid * 16;

#define STG(BUF, KH, KT) do { \
    GLD_LDS(Ag + (KT) + (KH) * 32,       AsD + ((BUF) * 2 + (KH)) * 8192); \
    GLD_LDS(Bg + (KT) + (KH) * 32,       BsD + ((BUF) * 2 + (KH)) * 16384); \
    GLD_LDS(Bg + (KT) + (KH) * 32 + rsk, BsD + ((BUF) * 2 + (KH)) * 16384 + 8192); \
  } while (0)

  STG(0, 0, 0); STG(0, 1, 0); STG(1, 0, 64);   // 9 outstanding

  const int swz = (l15 >> 1) & 3;

  for (int t = 0; t < NT; ++t) {
    const int c = t & 1;
    bf16x8 af[4], bfv[4];

    // kh0
    if (t < NT - 1) { asm volatile("s_waitcnt vmcnt(6)" ::: "memory"); }
    else            { asm volatile("s_waitcnt vmcnt(3)" ::: "memory"); }
    asm volatile("s_barrier" ::: "memory");
    #pragma unroll
    for (int mf = 0; mf < 4; ++mf)
      af[mf] = *(const bf16x8*)&Asm[c][0][wm * 64 + mf * 16 + l15][(l4 ^ swz) * 8];
    #pragma unroll
    for (int nf = 0; nf < 4; ++nf)
      bfv[nf] = *(const bf16x8*)&Bsm[c][0][wn * 64 + nf * 16 + l15][(l4 ^ swz) * 8];
    if (t + 1 < NT) STG(c ^ 1, 1, (t + 1) << 6);
    __builtin_amdgcn_s_setprio(1);
    #pragma unroll
    for (int mf = 0; mf < 4; ++mf)
      #pragma unroll
      for (int nf = 0; nf < 4; ++nf)
        acc[mf][nf] = __builtin_amdgcn_mfma_f32_16x16x32_bf16(af[mf], bfv[nf], acc[mf][nf], 0, 0, 0);
    __builtin_amdgcn_s_setprio(0);
    asm volatile("s_barrier" ::: "memory");

    // kh1
    if (t < NT - 1) { asm volatile("s_waitcnt vmcnt(6)" ::: "memory"); }
    else            { asm volatile("s_waitcnt vmcnt(0)" ::: "memory"); }
    asm volatile("s_barrier" ::: "memory");
    #pragma unroll
    for (int mf = 0; mf < 4; ++mf)
      af[mf] = *(const bf16x8*)&Asm[c][1][wm * 64 + mf * 16 + l15][(l4 ^ swz) * 8];
    #pragma unroll
    for (int nf = 0; nf < 4; ++nf)
      bfv[nf] = *(const bf16x8*)&Bsm[c][1][wn * 64 + nf * 16 + l15][(l4 ^ swz) * 8];
    if (t + 2 < NT) STG(c, 0, (t + 2) << 6);
    __builtin_amdgcn_s_setprio(1);
    #pragma unroll
    for (int mf = 0; mf < 4; ++mf)
      #pragma unroll
      for (int nf = 0; nf < 4; ++nf)
        acc[mf][nf] = __builtin_amdgcn_mfma_f32_16x16x32_bf16(af[mf], bfv[nf], acc[mf][nf], 0, 0, 0);
    __builtin_amdgcn_s_setprio(0);
    asm volatile("s_barrier" ::: "memory");
  }
#undef STG

  #pragma unroll
  for (int mf = 0; mf < 4; ++mf)
    #pragma unroll
    for (int nf = 0; nf < 4; ++nf)
      #pragma unroll
      for (int r = 0; r < 4; ++r) {
        int row = m0 + wm * 64 + mf * 16 + l4 * 4 + r;
        int col = n0 + wn * 64 + nf * 16 + l15;
        C[(size_t)row * N + col] = acc[mf][nf][r];
      }
}

// ---------------- RoPE + scatter (Q + K only; V handled in gemm_qkv epilogue) ----------------
__global__ __launch_bounds__(256) void rope_scatter(const u16* __restrict__ QKV,
    const float* __restrict__ cosT, const float* __restrict__ sinT,
    u16* __restrict__ Qr, u16* __restrict__ Kr, float* __restrict__ outK) {
  const float QSCALE = 0.125f * 1.44269504088896f;
  int row = blockIdx.x;            // b*2048 + t
  int b = row >> 11, t = row & 2047;
  const u16* src = QKV + (size_t)row * 3072;
  int tid = threadIdx.x;
  #pragma unroll
  for (int p = tid; p < 1024; p += 256) {
    int h = p >> 5, d = p & 31;
    float c = cosT[t * 32 + d], s = sinT[t * 32 + d];
    float q0 = bf2f(src[h * 64 + d]), q1 = bf2f(src[h * 64 + d + 32]);
    size_t base = ((size_t)(b * 32 + h) * 2048 + t) * 64 + d;
    Qr[base]      = f2bf((q0 * c - q1 * s) * QSCALE);
    Qr[base + 32] = f2bf((q1 * c + q0 * s) * QSCALE);
  }
  {
    int p = tid;                    // exactly 256 (g,d) pairs
    int gk = p >> 5, d = p & 31;
    float c = cosT[t * 32 + d], s = sinT[t * 32 + d];
    float k0 = bf2f(src[2048 + gk * 64 + d]), k1 = bf2f(src[2048 + gk * 64 + d + 32]);
    float r0 = k0 * c - k1 * s, r1 = k1 * c + k0 * s;
    size_t base = ((size_t)(b * 8 + gk) * 2048 + t) * 64 + d;
    Kr[base] = f2bf(r0); Kr[base + 32] = f2bf(r1);
    outK[base] = r0; outK[base + 32] = r1;
  }
}

// ---------------- flash attention (R14-proven bytes): swapped-operand 32x32x16, causal GQA ----------------
__global__ __launch_bounds__(256) void attn_kernel(
    const u16* __restrict__ Qr, const u16* __restrict__ Kr,
    const u16* __restrict__ Vt, u16* __restrict__ Ao) {
  __shared__ alignas(16) u16 Ks[2][64][72];   // [buf][kv][d] pitch 72
  __shared__ alignas(16) u16 Vs[2][64][72];   // [buf][d][kv] pitch 72

  const float FIXEDM = 24.0f;

  int bid = blockIdx.x;
  int pairI = bid >> 5;         // 0..15
  int sub = (bid >> 4) & 1;
  int g   = (bid >> 1) & 7;
  int b   = bid & 1;
  int tid = threadIdx.x;
  int w = tid >> 6, l = tid & 63;
  int l31 = l & 31, hi = l >> 5;
  int h = g * 4 + w;

  const u16* Kh = Kr + (size_t)(b * 8 + g) * 2048 * 64;
  const u16* Vh = Vt + (size_t)(b * 8 + g) * 64 * 2048;

  union { u16x8 u; bf16x8 v; } ones;
  #pragma unroll
  for (int i = 0; i < 8; ++i) ones.u[i] = 0x3F80;   // bf16 1.0

  int srow = tid >> 2, sc0 = (tid & 3) * 16;
  const u16* Kp = Kh + (size_t)srow * 64 + sc0;
  const u16* Vp = Vh + (size_t)srow * 2048 + sc0;

  for (int half = 0; half < 2; ++half) {
    const int qc  = half ? pairI : (31 - pairI);
    const int q0w = qc * 64 + sub * 32;
    const int qg  = q0w + l31;

    const u16* Qh = Qr + ((size_t)(b * 32 + h) * 2048 + q0w) * 64;
    bf16x8 qf[4];
    #pragma unroll
    for (int t = 0; t < 4; ++t)
      qf[t] = *reinterpret_cast<const bf16x8*>(Qh + (size_t)l31 * 64 + t * 16 + hi * 8);

    f32x16 o0 = {}, o1 = {}, lacc = {};

    if (half) __syncthreads();    // guard LDS reuse across halves

    {
      bf16x8 k0v = *reinterpret_cast<const bf16x8*>(Kp);
      bf16x8 k1v = *reinterpret_cast<const bf16x8*>(Kp + 8);
      bf16x8 v0v = *reinterpret_cast<const bf16x8*>(Vp);
      bf16x8 v1v = *reinterpret_cast<const bf16x8*>(Vp + 8);
      *reinterpret_cast<bf16x8*>(&Ks[0][srow][sc0]) = k0v;
      *reinterpret_cast<bf16x8*>(&Ks[0][srow][sc0 + 8]) = k1v;
      *reinterpret_cast<bf16x8*>(&Vs[0][srow][sc0]) = v0v;
      *reinterpret_cast<bf16x8*>(&Vs[0][srow][sc0 + 8]) = v1v;
    }
    __syncthreads();

    for (int s = 0; s <= qc; ++s) {
      int cur = s & 1;
      bf16x8 knx0, knx1, vnx0, vnx1;
      if (s < qc) {                                  // issue next-tile loads EARLY
        knx0 = *reinterpret_cast<const bf16x8*>(Kp + (size_t)(s + 1) * 4096);
        knx1 = *reinterpret_cast<const bf16x8*>(Kp + (size_t)(s + 1) * 4096 + 8);
        vnx0 = *reinterpret_cast<const bf16x8*>(Vp + (size_t)(s + 1) * 64);
        vnx1 = *reinterpret_cast<const bf16x8*>(Vp + (size_t)(s + 1) * 64 + 8);
      }
      int nh = (s == qc && sub == 0) ? 1 : 2;

      // seed C with -FIXEDM: S - 24 comes out of the MFMA chain for free
      f32x16 s0, s1;
      #pragma unroll
      for (int r = 0; r < 16; ++r) { s0[r] = -FIXEDM; s1[r] = -FIXEDM; }

      __builtin_amdgcn_s_setprio(1);
      #pragma unroll
      for (int t = 0; t < 4; ++t) {
        bf16x8 kf0 = *reinterpret_cast<const bf16x8*>(&Ks[cur][l31][t * 16 + hi * 8]);
        s0 = __builtin_amdgcn_mfma_f32_32x32x16_bf16(kf0, qf[t], s0, 0, 0, 0);
      }
      if (nh == 2) {
        #pragma unroll
        for (int t = 0; t < 4; ++t) {
          bf16x8 kf1 = *reinterpret_cast<const bf16x8*>(&Ks[cur][32 + l31][t * 16 + hi * 8]);
          s1 = __builtin_amdgcn_mfma_f32_32x32x16_bf16(kf1, qf[t], s1, 0, 0, 0);
        }
      }
      __builtin_amdgcn_s_setprio(0);

      if (s == qc) {
        #pragma unroll
        for (int r = 0; r < 16; ++r) {
          int kvg = s * 64 + (r & 3) + (r >> 2) * 8 + hi * 4;
          if (kvg > qg) s0[r] = -INFINITY;
        }
        if (nh == 2) {
          #pragma unroll
          for (int r = 0; r < 16; ++r) {
            int kvg = s * 64 + 32 + (r & 3) + (r >> 2) * 8 + hi * 4;
            if (kvg > qg) s1[r] = -INFINITY;
          }
        }
      }

      // p = 2^(S - 24); masked (-inf) -> 0
      float p0[16], p1[16];
      #pragma unroll
      for (int r = 0; r < 16; ++r) p0[r] = fexp2(s0[r]);
      if (nh == 2) {
        #pragma unroll
        for (int r = 0; r < 16; ++r) p1[r] = fexp2(s1[r]);
      }

      // pack P -> bf16 pairs; group gi covers kv = 8*gi + 4*hi + {0..3}
      uint32_t pkA[8], pkB[8];
      #pragma unroll
      for (int gi = 0; gi < 8; ++gi) {
        if (gi < nh * 4) {
          const float* pp = (gi < 4) ? p0 : p1;
          int base = (gi & 3) * 4;
          pkA[gi] = pk2(pp[base + 0], pp[base + 1]);
          pkB[gi] = pk2(pp[base + 2], pp[base + 3]);
        }
      }
      __builtin_amdgcn_s_setprio(1);
      #pragma unroll
      for (int kc = 0; kc < 4; ++kc) {
        if (kc < nh * 2) {
          uint32_t wd0 = pkA[kc * 2], wd2 = pkA[kc * 2 + 1];
          PSWAP(wd0, wd2);
          uint32_t wd1 = pkB[kc * 2], wd3 = pkB[kc * 2 + 1];
          PSWAP(wd1, wd3);
          union { uint32_t wd[4]; bf16x8 v; } pb;
          pb.wd[0] = wd0; pb.wd[1] = wd1; pb.wd[2] = wd2; pb.wd[3] = wd3;
          bf16x8 va0 = *reinterpret_cast<const bf16x8*>(&Vs[cur][l31][kc * 16 + hi * 8]);
          bf16x8 va1 = *reinterpret_cast<const bf16x8*>(&Vs[cur][32 + l31][kc * 16 + hi * 8]);
          o0 = __builtin_amdgcn_mfma_f32_32x32x16_bf16(va0, pb.v, o0, 0, 0, 0);
          o1 = __builtin_amdgcn_mfma_f32_32x32x16_bf16(va1, pb.v, o1, 0, 0, 0);
          lacc = __builtin_amdgcn_mfma_f32_32x32x16_bf16(ones.v, pb.v, lacc, 0, 0, 0);
        }
      }
      __builtin_amdgcn_s_setprio(0);

      if (s < qc) {                                   // write next tile, ONE barrier/iter
        *reinterpret_cast<bf16x8*>(&Ks[cur ^ 1][srow][sc0]) = knx0;
        *reinterpret_cast<bf16x8*>(&Ks[cur ^ 1][srow][sc0 + 8]) = knx1;
        *reinterpret_cast<bf16x8*>(&Vs[cur ^ 1][srow][sc0]) = vnx0;
        *reinterpret_cast<bf16x8*>(&Vs[cur ^ 1][srow][sc0 + 8]) = vnx1;
        __syncthreads();
      }
    }

    float inv = 1.0f / lacc[0];     // all lacc rows equal: column sum of P
    int token = b * 2048 + q0w + l31;
    u16* dst = Ao + (size_t)token * 2048 + h * 64;
    #pragma unroll
    for (int hf = 0; hf < 2; ++hf) {
      f32x16 ov = hf ? o1 : o0;
      #pragma unroll
      for (int r = 0; r < 16; r += 2) {
        int d = (r & 3) + (r >> 2) * 8 + hi * 4 + hf * 32;
        *reinterpret_cast<uint32_t*>(dst + d) = pk2(ov[r] * inv, ov[r + 1] * inv);
      }
    }
  }
}

extern "C" void kernel_launch(void* const* d_in, const int* in_sizes, int n_in,
                              void* d_out, int out_size, void* d_ws, size_t ws_size,
                              hipStream_t stream) {
  const float* x  = (const float*)d_in[0];
  const float* Wq = (const float*)d_in[1];
  const float* Wk = (const float*)d_in[2];
  const float* Wv = (const float*)d_in[3];
  const float* Wo = (const float*)d_in[4];
  float* out = (float*)d_out;

  char* ws = (char*)d_ws;
  u16*   Xb    = (u16*)(ws + 0);              // [4096][2048] bf16
  u16*   Wcat  = (u16*)(ws + 16777216);       // [3072][2048] bf16 = {Wq^T, Wk^T, Wv^T}
  u16*   WoT   = (u16*)(ws + 29360128);       // [2048][2048] bf16
  u16*   QKV   = (u16*)(ws + 37748736);       // [4096][3072] bf16 (aliased by AttnB after rope)
  u16*   AttnB = (u16*)(ws + 37748736);       // [4096][2048] bf16
  u16*   Qr    = (u16*)(ws + 88080384);       // [2][32][2048][64] bf16 (exp2-domain scaled)
  u16*   Kr    = (u16*)(ws + 104857600);      // [2][8][2048][64] bf16
  u16*   Vtr   = (u16*)(ws + 109051904);      // [2][8][64][2048] bf16
  float* cosT  = (float*)(ws + 113246208);    // [2048][32]
  float* sinT  = (float*)(ws + 113508352);    // [2048][32]

  float* outK = out + 8388608;
  float* outV = out + 10485760;

  prep_all<<<12544, 256, 0, stream>>>(x, Xb, Wq, Wk, Wv, Wo, Wcat, WoT, cosT, sinT);
  gemm_qkv<<<dim3(12, 16), 512, 0, stream>>>(Xb, Wcat, QKV, Vtr);
  v_upcast<<<dim3(32, 16), 256, 0, stream>>>(Vtr, outV);
  rope_scatter<<<4096, 256, 0, stream>>>(QKV, cosT, sinT, Qr, Kr, outK);
  attn_kernel<<<512, 256, 0, stream>>>(Qr, Kr, Vtr, AttnB);
  gemm128<<<dim3(8, 32), 512, 0, stream>>>(AttnB, WoT, out, 4096, 2048, 2048);
}

// Round 23
// 191.083 us; speedup vs baseline: 1.0189x; 1.0189x over previous
//
#include <hip/hip_runtime.h>
#include <hip/hip_bf16.h>
#include <cstdint>

typedef uint16_t u16;
typedef __attribute__((ext_vector_type(8))) __bf16 bf16x8;
typedef __attribute__((ext_vector_type(4))) float f32x4;
typedef __attribute__((ext_vector_type(16))) float f32x16;
typedef __attribute__((ext_vector_type(8))) unsigned short u16x8;

#define GLD_LDS(SRC, DST) \
  __builtin_amdgcn_global_load_lds((const __attribute__((address_space(1))) void*)(SRC), \
                                   (__attribute__((address_space(3))) void*)(DST), 16, 0, 0)

// v_permlane32_swap_b32 d, s: new_d = {d.lo31, s.lo31}, new_s = {d.hi31, s.hi31}
#define PSWAP(d, s) asm volatile("v_permlane32_swap_b32 %0, %1" : "+v"(d), "+v"(s))

__device__ __forceinline__ u16 f2bf(float f) {
  uint32_t u = __float_as_uint(f);
  u += 0x7fffu + ((u >> 16) & 1u);   // RNE; inputs are finite
  return (u16)(u >> 16);
}

__device__ __forceinline__ float bf2f(u16 u) {
  return __uint_as_float(((uint32_t)u) << 16);
}

__device__ __forceinline__ uint32_t pk2(float a, float b) {
  union { __bf16 h[2]; uint32_t u; } x;
  x.h[0] = (__bf16)a; x.h[1] = (__bf16)b;
  return x.u;
}

__device__ __forceinline__ float fexp2(float x) {
#if __has_builtin(__builtin_amdgcn_exp2f)
  return __builtin_amdgcn_exp2f(x);
#else
  return exp2f(x);
#endif
}

// ---------------- fused prep: cast x, transpose Wq/Wk/Wv/Wo, rope tables ----------------
__global__ __launch_bounds__(256) void prep_all(const float* __restrict__ x, u16* __restrict__ Xb,
    const float* __restrict__ Wq, const float* __restrict__ Wk, const float* __restrict__ Wv,
    const float* __restrict__ Wo, u16* __restrict__ Wcat, u16* __restrict__ WoT,
    float* __restrict__ cosT, float* __restrict__ sinT) {
  int bid = blockIdx.x, tid = threadIdx.x;
  if (bid < 2048) {                     // cast: 4 float4 / thread
    int base = bid * 1024 + tid;
    #pragma unroll
    for (int k = 0; k < 4; ++k) {
      int i = base + k * 256;
      float4 v = reinterpret_cast<const float4*>(x)[i];
      ushort4 o;
      o.x = f2bf(v.x); o.y = f2bf(v.y); o.z = f2bf(v.z); o.w = f2bf(v.w);
      reinterpret_cast<ushort4*>(Xb)[i] = o;
    }
    return;
  }
  if (bid >= 8192 && bid < 8448) {      // rope tables: 8 t per block
    int b2 = bid - 8192;
    int t = b2 * 8 + (tid >> 5), i = tid & 31;
    float invf = powf(10000.0f, -(float)i * (1.0f / 32.0f));
    float ang = (float)t * invf;
    cosT[t * 32 + i] = cosf(ang);
    sinT[t * 32 + i] = sinf(ang);
    return;
  }
  __shared__ float tile[32][33];
  const float* W; u16* Wt; int N, bx, by;
  if (bid < 6144)      { int b2 = bid - 2048; W = Wq; Wt = Wcat;               N = 2048; bx = b2 & 63; by = b2 >> 6; }
  else if (bid < 7168) { int b2 = bid - 6144; W = Wk; Wt = Wcat + 2048 * 2048; N = 512;  bx = b2 & 15; by = b2 >> 4; }
  else if (bid < 8192) { int b2 = bid - 7168; W = Wv; Wt = Wcat + 2560 * 2048; N = 512;  bx = b2 & 15; by = b2 >> 4; }
  else                 { int b2 = bid - 8448; W = Wo; Wt = WoT;                N = 2048; bx = b2 & 63; by = b2 >> 6; }
  int n0 = bx * 32, k0 = by * 32;
  int tx = tid & 31, ty = tid >> 5;
  #pragma unroll
  for (int i = ty; i < 32; i += 8)
    tile[i][tx] = W[(size_t)(k0 + i) * N + n0 + tx];
  __syncthreads();
  #pragma unroll
  for (int i = ty; i < 32; i += 8)
    Wt[(size_t)(n0 + i) * 2048 + k0 + tx] = f2bf(tile[tx][i]);
}

// ---------------- QKV GEMM: 256^2 tile, paired-phase (R14-proven core) ----------------
// V epilogue (blocks bx>=10): LDS-transpose (reusing staging LDS) -> coalesced Vtr
// bf16 writes; outV fp32 written direct (64B segments). Other blocks write Cq.
__global__ __launch_bounds__(512, 2) void gemm_qkv(const u16* __restrict__ A,
    const u16* __restrict__ Bt, u16* __restrict__ Cq,
    u16* __restrict__ Vtr, float* __restrict__ outV) {
  __shared__ alignas(16) u16 Asm[2][2][256][32];   // 64 KB
  __shared__ alignas(16) u16 Bsm[2][2][256][32];   // 64 KB

  const int K = 2048, N = 3072;
  const int tid = threadIdx.x;
  const int l = tid & 63;
  const int w = tid >> 6;
  const int wm = w >> 2, wn = w & 3;
  const int l15 = l & 15, l4 = l >> 4;
  const int m0 = blockIdx.y * 256, n0 = blockIdx.x * 256;
  const int NT = K >> 6;               // 32

  f32x4 acc[8][4] = {};

  const int srow = tid >> 2;
  const int sg   = (tid & 3) ^ ((srow >> 1) & 3);
  const u16* Ag = A + (size_t)(m0 + srow) * K + sg * 8;
  const u16* Bg = Bt + (size_t)(n0 + srow) * K + sg * 8;
  const size_t rsk = (size_t)128 * K;
  char* AsD = (char*)&Asm[0][0][0][0] + tid * 16;
  char* BsD = (char*)&Bsm[0][0][0][0] + tid * 16;

#define STAGE_A(BUF, KH, KT) do { \
    GLD_LDS(Ag + (KT) + (KH) * 32,       AsD + ((BUF) * 2 + (KH)) * 16384); \
    GLD_LDS(Ag + (KT) + (KH) * 32 + rsk, AsD + ((BUF) * 2 + (KH)) * 16384 + 8192); \
  } while (0)
#define STAGE_B(BUF, KH, KT) do { \
    GLD_LDS(Bg + (KT) + (KH) * 32,       BsD + ((BUF) * 2 + (KH)) * 16384); \
    GLD_LDS(Bg + (KT) + (KH) * 32 + rsk, BsD + ((BUF) * 2 + (KH)) * 16384 + 8192); \
  } while (0)

  STAGE_A(0, 0, 0);  STAGE_B(0, 0, 0);
  STAGE_A(0, 1, 0);  STAGE_B(0, 1, 0);
  STAGE_A(1, 0, 64); STAGE_B(1, 0, 64);   // 12 outstanding

  const int swz = (l15 >> 1) & 3;

  for (int t = 0; t < NT; ++t) {
    const int c = t & 1;
    const int ktn  = (t + 1) << 6;
    const int ktn2 = (t + 2) << 6;
    bf16x8 bfv[4], af0[4], af1[4];

    // ---------- Phase A: kh=0, both mh halves ----------
    if (t < NT - 1) { asm volatile("s_waitcnt vmcnt(8)" ::: "memory"); }
    else            { asm volatile("s_waitcnt vmcnt(4)" ::: "memory"); }
    asm volatile("s_barrier" ::: "memory");
    #pragma unroll
    for (int nf = 0; nf < 4; ++nf)
      bfv[nf] = *(const bf16x8*)&Bsm[c][0][wn * 64 + nf * 16 + l15][(l4 ^ swz) * 8];
    #pragma unroll
    for (int mf = 0; mf < 4; ++mf)
      af0[mf] = *(const bf16x8*)&Asm[c][0][wm * 128 + mf * 16 + l15][(l4 ^ swz) * 8];
    if (t + 1 < NT) STAGE_A(c ^ 1, 1, ktn);
    #pragma unroll
    for (int mf = 0; mf < 4; ++mf)     // issued early; land under p0 MFMAs
      af1[mf] = *(const bf16x8*)&Asm[c][0][wm * 128 + 64 + mf * 16 + l15][(l4 ^ swz) * 8];
    __builtin_amdgcn_s_setprio(1);
    #pragma unroll
    for (int mf = 0; mf < 4; ++mf)
      #pragma unroll
      for (int nf = 0; nf < 4; ++nf)
        acc[mf][nf] = __builtin_amdgcn_mfma_f32_16x16x32_bf16(af0[mf], bfv[nf], acc[mf][nf], 0, 0, 0);
    __builtin_amdgcn_s_setprio(0);
    if (t + 1 < NT) STAGE_B(c ^ 1, 1, ktn);
    __builtin_amdgcn_s_setprio(1);
    #pragma unroll
    for (int mf = 0; mf < 4; ++mf)
      #pragma unroll
      for (int nf = 0; nf < 4; ++nf)
        acc[4 + mf][nf] = __builtin_amdgcn_mfma_f32_16x16x32_bf16(af1[mf], bfv[nf], acc[4 + mf][nf], 0, 0, 0);
    __builtin_amdgcn_s_setprio(0);
    asm volatile("s_barrier" ::: "memory");

    // ---------- Phase B: kh=1, both mh halves ----------
    if (t < NT - 1) { asm volatile("s_waitcnt vmcnt(8)" ::: "memory"); }
    else            { asm volatile("s_waitcnt vmcnt(0)" ::: "memory"); }
    asm volatile("s_barrier" ::: "memory");
    #pragma unroll
    for (int nf = 0; nf < 4; ++nf)
      bfv[nf] = *(const bf16x8*)&Bsm[c][1][wn * 64 + nf * 16 + l15][(l4 ^ swz) * 8];
    #pragma unroll
    for (int mf = 0; mf < 4; ++mf)
      af0[mf] = *(const bf16x8*)&Asm[c][1][wm * 128 + mf * 16 + l15][(l4 ^ swz) * 8];
    if (t + 2 < NT) STAGE_A(c, 0, ktn2);
    #pragma unroll
    for (int mf = 0; mf < 4; ++mf)
      af1[mf] = *(const bf16x8*)&Asm[c][1][wm * 128 + 64 + mf * 16 + l15][(l4 ^ swz) * 8];
    __builtin_amdgcn_s_setprio(1);
    #pragma unroll
    for (int mf = 0; mf < 4; ++mf)
      #pragma unroll
      for (int nf = 0; nf < 4; ++nf)
        acc[mf][nf] = __builtin_amdgcn_mfma_f32_16x16x32_bf16(af0[mf], bfv[nf], acc[mf][nf], 0, 0, 0);
    __builtin_amdgcn_s_setprio(0);
    if (t + 2 < NT) STAGE_B(c, 0, ktn2);
    __builtin_amdgcn_s_setprio(1);
    #pragma unroll
    for (int mf = 0; mf < 4; ++mf)
      #pragma unroll
      for (int nf = 0; nf < 4; ++nf)
        acc[4 + mf][nf] = __builtin_amdgcn_mfma_f32_16x16x32_bf16(af1[mf], bfv[nf], acc[4 + mf][nf], 0, 0, 0);
    __builtin_amdgcn_s_setprio(0);
    asm volatile("s_barrier" ::: "memory");
  }
#undef STAGE_A
#undef STAGE_B

  if (blockIdx.x >= 10) {
    // ---- V epilogue: transpose through (dead) staging LDS, then coalesced stores ----
    const int b   = m0 >> 11;
    const int tb  = m0 & 2047;                 // t base of this block
    const int gvb = (blockIdx.x - 10) * 4;     // kv-group base (bx=10 -> 0, bx=11 -> 4)
    char* ldsA = (char*)&Asm[0][0][0][0];      // c2 <  128 : 64 KB, pitch 512 B
    char* ldsB = (char*)&Bsm[0][0][0][0];      // c2 >= 128 : 64 KB
    // write: bf16 pairs at [c2][t] with XOR swizzle (2-way banks = free)
    #pragma unroll
    for (int mi = 0; mi < 8; ++mi)
      #pragma unroll
      for (int nf = 0; nf < 4; ++nf) {
        int c2 = wn * 64 + nf * 16 + l15;      // 0..255 (uniform array select per wave)
        int tloc = wm * 128 + mi * 16 + l4 * 4;
        char* base = (c2 & 128) ? ldsB : ldsA;
        uint32_t byte = (uint32_t)(c2 & 127) * 512 +
                        (((uint32_t)tloc * 2) ^ ((uint32_t)(c2 & 7) << 4));
        union { uint32_t w2[2]; uint64_t q; } pq;
        pq.w2[0] = pk2(acc[mi][nf][0], acc[mi][nf][1]);
        pq.w2[1] = pk2(acc[mi][nf][2], acc[mi][nf][3]);
        *reinterpret_cast<uint64_t*>(base + byte) = pq.q;
        // outV fp32 direct (16 lanes x 4B = 64B segments)
        int gv = c2 >> 6, d = c2 & 63;
        float* ov = outV + (((size_t)(b * 8 + gvb + gv) * 2048) + tb + tloc) * 64 + d;
        #pragma unroll
        for (int r = 0; r < 4; ++r)
          ov[(size_t)r * 64] = acc[mi][nf][r];
      }
    __syncthreads();
    // read coalesced (16B chunks along t) + wide global store (512B runs per 32 lanes)
    #pragma unroll
    for (int it = 0; it < 16; ++it) {
      int chunk = tid + it * 512;              // 0..8191 ; array select uniform per wave
      int c2 = chunk >> 5;
      int tc = chunk & 31;
      char* base = (c2 & 128) ? ldsB : ldsA;
      uint32_t byte = (uint32_t)(c2 & 127) * 512 +
                      (((uint32_t)tc * 16) ^ ((uint32_t)(c2 & 7) << 4));
      bf16x8 v = *reinterpret_cast<const bf16x8*>(base + byte);
      int gv = c2 >> 6, d = c2 & 63;
      u16* vt = Vtr + (size_t)(b * 8 + gvb + gv) * 64 * 2048 + (size_t)d * 2048 + tb + tc * 8;
      *reinterpret_cast<bf16x8*>(vt) = v;
    }
  } else {
    #pragma unroll
    for (int mi = 0; mi < 8; ++mi)
      #pragma unroll
      for (int nf = 0; nf < 4; ++nf)
        #pragma unroll
        for (int r = 0; r < 4; ++r) {
          int row = m0 + wm * 128 + mi * 16 + l4 * 4 + r;
          int col = n0 + wn * 64 + nf * 16 + l15;
          Cq[(size_t)row * N + col] = f2bf(acc[mi][nf][r]);
        }
  }
}

// ---------------- 128x256-tile GEMM (f32 out), split-phase (R14-proven) ----------------
__global__ __launch_bounds__(512, 2) void gemm128(const u16* __restrict__ A,
    const u16* __restrict__ Bt, float* __restrict__ C, int M, int N, int K) {
  __shared__ alignas(16) u16 Asm[2][2][128][32];   // 32 KB
  __shared__ alignas(16) u16 Bsm[2][2][256][32];   // 64 KB

  const int tid = threadIdx.x;
  const int l = tid & 63;
  const int w = tid >> 6;
  const int wm = w >> 2, wn = w & 3;
  const int l15 = l & 15, l4 = l >> 4;
  const int m0 = blockIdx.y * 128, n0 = blockIdx.x * 256;
  const int NT = K >> 6;

  f32x4 acc[4][4] = {};

  const int srow = tid >> 2;
  const int sg   = (tid & 3) ^ ((srow >> 1) & 3);
  const u16* Ag = A + (size_t)(m0 + srow) * K + sg * 8;
  const u16* Bg = Bt + (size_t)(n0 + srow) * K + sg * 8;
  const size_t rsk = (size_t)128 * K;
  char* AsD = (char*)&Asm[0][0][0][0] + tid * 16;
  char* BsD = (char*)&Bsm[0][0][0][0] + tid * 16;

#define STG(BUF, KH, KT) do { \
    GLD_LDS(Ag + (KT) + (KH) * 32,       AsD + ((BUF) * 2 + (KH)) * 8192); \
    GLD_LDS(Bg + (KT) + (KH) * 32,       BsD + ((BUF) * 2 + (KH)) * 16384); \
    GLD_LDS(Bg + (KT) + (KH) * 32 + rsk, BsD + ((BUF) * 2 + (KH)) * 16384 + 8192); \
  } while (0)

  STG(0, 0, 0); STG(0, 1, 0); STG(1, 0, 64);   // 9 outstanding

  const int swz = (l15 >> 1) & 3;

  for (int t = 0; t < NT; ++t) {
    const int c = t & 1;
    bf16x8 af[4], bfv[4];

    // kh0
    if (t < NT - 1) { asm volatile("s_waitcnt vmcnt(6)" ::: "memory"); }
    else            { asm volatile("s_waitcnt vmcnt(3)" ::: "memory"); }
    asm volatile("s_barrier" ::: "memory");
    #pragma unroll
    for (int mf = 0; mf < 4; ++mf)
      af[mf] = *(const bf16x8*)&Asm[c][0][wm * 64 + mf * 16 + l15][(l4 ^ swz) * 8];
    #pragma unroll
    for (int nf = 0; nf < 4; ++nf)
      bfv[nf] = *(const bf16x8*)&Bsm[c][0][wn * 64 + nf * 16 + l15][(l4 ^ swz) * 8];
    if (t + 1 < NT) STG(c ^ 1, 1, (t + 1) << 6);
    __builtin_amdgcn_s_setprio(1);
    #pragma unroll
    for (int mf = 0; mf < 4; ++mf)
      #pragma unroll
      for (int nf = 0; nf < 4; ++nf)
        acc[mf][nf] = __builtin_amdgcn_mfma_f32_16x16x32_bf16(af[mf], bfv[nf], acc[mf][nf], 0, 0, 0);
    __builtin_amdgcn_s_setprio(0);
    asm volatile("s_barrier" ::: "memory");

    // kh1
    if (t < NT - 1) { asm volatile("s_waitcnt vmcnt(6)" ::: "memory"); }
    else            { asm volatile("s_waitcnt vmcnt(0)" ::: "memory"); }
    asm volatile("s_barrier" ::: "memory");
    #pragma unroll
    for (int mf = 0; mf < 4; ++mf)
      af[mf] = *(const bf16x8*)&Asm[c][1][wm * 64 + mf * 16 + l15][(l4 ^ swz) * 8];
    #pragma unroll
    for (int nf = 0; nf < 4; ++nf)
      bfv[nf] = *(const bf16x8*)&Bsm[c][1][wn * 64 + nf * 16 + l15][(l4 ^ swz) * 8];
    if (t + 2 < NT) STG(c, 0, (t + 2) << 6);
    __builtin_amdgcn_s_setprio(1);
    #pragma unroll
    for (int mf = 0; mf < 4; ++mf)
      #pragma unroll
      for (int nf = 0; nf < 4; ++nf)
        acc[mf][nf] = __builtin_amdgcn_mfma_f32_16x16x32_bf16(af[mf], bfv[nf], acc[mf][nf], 0, 0, 0);
    __builtin_amdgcn_s_setprio(0);
    asm volatile("s_barrier" ::: "memory");
  }
#undef STG

  #pragma unroll
  for (int mf = 0; mf < 4; ++mf)
    #pragma unroll
    for (int nf = 0; nf < 4; ++nf)
      #pragma unroll
      for (int r = 0; r < 4; ++r) {
        int row = m0 + wm * 64 + mf * 16 + l4 * 4 + r;
        int col = n0 + wn * 64 + nf * 16 + l15;
        C[(size_t)row * N + col] = acc[mf][nf][r];
      }
}

// ---------------- RoPE + scatter (Q + K only; V handled in gemm_qkv epilogue) ----------------
__global__ __launch_bounds__(256) void rope_scatter(const u16* __restrict__ QKV,
    const float* __restrict__ cosT, const float* __restrict__ sinT,
    u16* __restrict__ Qr, u16* __restrict__ Kr, float* __restrict__ outK) {
  const float QSCALE = 0.125f * 1.44269504088896f;
  int row = blockIdx.x;            // b*2048 + t
  int b = row >> 11, t = row & 2047;
  const u16* src = QKV + (size_t)row * 3072;
  int tid = threadIdx.x;
  #pragma unroll
  for (int p = tid; p < 1024; p += 256) {
    int h = p >> 5, d = p & 31;
    float c = cosT[t * 32 + d], s = sinT[t * 32 + d];
    float q0 = bf2f(src[h * 64 + d]), q1 = bf2f(src[h * 64 + d + 32]);
    size_t base = ((size_t)(b * 32 + h) * 2048 + t) * 64 + d;
    Qr[base]      = f2bf((q0 * c - q1 * s) * QSCALE);
    Qr[base + 32] = f2bf((q1 * c + q0 * s) * QSCALE);
  }
  {
    int p = tid;                    // exactly 256 (g,d) pairs
    int gk = p >> 5, d = p & 31;
    float c = cosT[t * 32 + d], s = sinT[t * 32 + d];
    float k0 = bf2f(src[2048 + gk * 64 + d]), k1 = bf2f(src[2048 + gk * 64 + d + 32]);
    float r0 = k0 * c - k1 * s, r1 = k1 * c + k0 * s;
    size_t base = ((size_t)(b * 8 + gk) * 2048 + t) * 64 + d;
    Kr[base] = f2bf(r0); Kr[base + 32] = f2bf(r1);
    outK[base] = r0; outK[base + 32] = r1;
  }
}

// ---------------- flash attention (R14-proven bytes): swapped-operand 32x32x16, causal GQA ----------------
__global__ __launch_bounds__(256) void attn_kernel(
    const u16* __restrict__ Qr, const u16* __restrict__ Kr,
    const u16* __restrict__ Vt, u16* __restrict__ Ao) {
  __shared__ alignas(16) u16 Ks[2][64][72];   // [buf][kv][d] pitch 72
  __shared__ alignas(16) u16 Vs[2][64][72];   // [buf][d][kv] pitch 72

  const float FIXEDM = 24.0f;

  int bid = blockIdx.x;
  int pairI = bid >> 5;         // 0..15
  int sub = (bid >> 4) & 1;
  int g   = (bid >> 1) & 7;
  int b   = bid & 1;
  int tid = threadIdx.x;
  int w = tid >> 6, l = tid & 63;
  int l31 = l & 31, hi = l >> 5;
  int h = g * 4 + w;

  const u16* Kh = Kr + (size_t)(b * 8 + g) * 2048 * 64;
  const u16* Vh = Vt + (size_t)(b * 8 + g) * 64 * 2048;

  union { u16x8 u; bf16x8 v; } ones;
  #pragma unroll
  for (int i = 0; i < 8; ++i) ones.u[i] = 0x3F80;   // bf16 1.0

  int srow = tid >> 2, sc0 = (tid & 3) * 16;
  const u16* Kp = Kh + (size_t)srow * 64 + sc0;
  const u16* Vp = Vh + (size_t)srow * 2048 + sc0;

  for (int half = 0; half < 2; ++half) {
    const int qc  = half ? pairI : (31 - pairI);
    const int q0w = qc * 64 + sub * 32;
    const int qg  = q0w + l31;

    const u16* Qh = Qr + ((size_t)(b * 32 + h) * 2048 + q0w) * 64;
    bf16x8 qf[4];
    #pragma unroll
    for (int t = 0; t < 4; ++t)
      qf[t] = *reinterpret_cast<const bf16x8*>(Qh + (size_t)l31 * 64 + t * 16 + hi * 8);

    f32x16 o0 = {}, o1 = {}, lacc = {};

    if (half) __syncthreads();    // guard LDS reuse across halves

    {
      bf16x8 k0v = *reinterpret_cast<const bf16x8*>(Kp);
      bf16x8 k1v = *reinterpret_cast<const bf16x8*>(Kp + 8);
      bf16x8 v0v = *reinterpret_cast<const bf16x8*>(Vp);
      bf16x8 v1v = *reinterpret_cast<const bf16x8*>(Vp + 8);
      *reinterpret_cast<bf16x8*>(&Ks[0][srow][sc0]) = k0v;
      *reinterpret_cast<bf16x8*>(&Ks[0][srow][sc0 + 8]) = k1v;
      *reinterpret_cast<bf16x8*>(&Vs[0][srow][sc0]) = v0v;
      *reinterpret_cast<bf16x8*>(&Vs[0][srow][sc0 + 8]) = v1v;
    }
    __syncthreads();

    for (int s = 0; s <= qc; ++s) {
      int cur = s & 1;
      bf16x8 knx0, knx1, vnx0, vnx1;
      if (s < qc) {                                  // issue next-tile loads EARLY
        knx0 = *reinterpret_cast<const bf16x8*>(Kp + (size_t)(s + 1) * 4096);
        knx1 = *reinterpret_cast<const bf16x8*>(Kp + (size_t)(s + 1) * 4096 + 8);
        vnx0 = *reinterpret_cast<const bf16x8*>(Vp + (size_t)(s + 1) * 64);
        vnx1 = *reinterpret_cast<const bf16x8*>(Vp + (size_t)(s + 1) * 64 + 8);
      }
      int nh = (s == qc && sub == 0) ? 1 : 2;

      // seed C with -FIXEDM: S - 24 comes out of the MFMA chain for free
      f32x16 s0, s1;
      #pragma unroll
      for (int r = 0; r < 16; ++r) { s0[r] = -FIXEDM; s1[r] = -FIXEDM; }

      __builtin_amdgcn_s_setprio(1);
      #pragma unroll
      for (int t = 0; t < 4; ++t) {
        bf16x8 kf0 = *reinterpret_cast<const bf16x8*>(&Ks[cur][l31][t * 16 + hi * 8]);
        s0 = __builtin_amdgcn_mfma_f32_32x32x16_bf16(kf0, qf[t], s0, 0, 0, 0);
      }
      if (nh == 2) {
        #pragma unroll
        for (int t = 0; t < 4; ++t) {
          bf16x8 kf1 = *reinterpret_cast<const bf16x8*>(&Ks[cur][32 + l31][t * 16 + hi * 8]);
          s1 = __builtin_amdgcn_mfma_f32_32x32x16_bf16(kf1, qf[t], s1, 0, 0, 0);
        }
      }
      __builtin_amdgcn_s_setprio(0);

      if (s == qc) {
        #pragma unroll
        for (int r = 0; r < 16; ++r) {
          int kvg = s * 64 + (r & 3) + (r >> 2) * 8 + hi * 4;
          if (kvg > qg) s0[r] = -INFINITY;
        }
        if (nh == 2) {
          #pragma unroll
          for (int r = 0; r < 16; ++r) {
            int kvg = s * 64 + 32 + (r & 3) + (r >> 2) * 8 + hi * 4;
            if (kvg > qg) s1[r] = -INFINITY;
          }
        }
      }

      // p = 2^(S - 24); masked (-inf) -> 0
      float p0[16], p1[16];
      #pragma unroll
      for (int r = 0; r < 16; ++r) p0[r] = fexp2(s0[r]);
      if (nh == 2) {
        #pragma unroll
        for (int r = 0; r < 16; ++r) p1[r] = fexp2(s1[r]);
      }

      // pack P -> bf16 pairs; group gi covers kv = 8*gi + 4*hi + {0..3}
      uint32_t pkA[8], pkB[8];
      #pragma unroll
      for (int gi = 0; gi < 8; ++gi) {
        if (gi < nh * 4) {
          const float* pp = (gi < 4) ? p0 : p1;
          int base = (gi & 3) * 4;
          pkA[gi] = pk2(pp[base + 0], pp[base + 1]);
          pkB[gi] = pk2(pp[base + 2], pp[base + 3]);
        }
      }
      __builtin_amdgcn_s_setprio(1);
      #pragma unroll
      for (int kc = 0; kc < 4; ++kc) {
        if (kc < nh * 2) {
          uint32_t wd0 = pkA[kc * 2], wd2 = pkA[kc * 2 + 1];
          PSWAP(wd0, wd2);
          uint32_t wd1 = pkB[kc * 2], wd3 = pkB[kc * 2 + 1];
          PSWAP(wd1, wd3);
          union { uint32_t wd[4]; bf16x8 v; } pb;
          pb.wd[0] = wd0; pb.wd[1] = wd1; pb.wd[2] = wd2; pb.wd[3] = wd3;
          bf16x8 va0 = *reinterpret_cast<const bf16x8*>(&Vs[cur][l31][kc * 16 + hi * 8]);
          bf16x8 va1 = *reinterpret_cast<const bf16x8*>(&Vs[cur][32 + l31][kc * 16 + hi * 8]);
          o0 = __builtin_amdgcn_mfma_f32_32x32x16_bf16(va0, pb.v, o0, 0, 0, 0);
          o1 = __builtin_amdgcn_mfma_f32_32x32x16_bf16(va1, pb.v, o1, 0, 0, 0);
          lacc = __builtin_amdgcn_mfma_f32_32x32x16_bf16(ones.v, pb.v, lacc, 0, 0, 0);
        }
      }
      __builtin_amdgcn_s_setprio(0);

      if (s < qc) {                                   // write next tile, ONE barrier/iter
        *reinterpret_cast<bf16x8*>(&Ks[cur ^ 1][srow][sc0]) = knx0;
        *reinterpret_cast<bf16x8*>(&Ks[cur ^ 1][srow][sc0 + 8]) = knx1;
        *reinterpret_cast<bf16x8*>(&Vs[cur ^ 1][srow][sc0]) = vnx0;
        *reinterpret_cast<bf16x8*>(&Vs[cur ^ 1][srow][sc0 + 8]) = vnx1;
        __syncthreads();
      }
    }

    float inv = 1.0f / lacc[0];     // all lacc rows equal: column sum of P
    int token = b * 2048 + q0w + l31;
    u16* dst = Ao + (size_t)token * 2048 + h * 64;
    #pragma unroll
    for (int hf = 0; hf < 2; ++hf) {
      f32x16 ov = hf ? o1 : o0;
      #pragma unroll
      for (int r = 0; r < 16; r += 2) {
        int d = (r & 3) + (r >> 2) * 8 + hi * 4 + hf * 32;
        *reinterpret_cast<uint32_t*>(dst + d) = pk2(ov[r] * inv, ov[r + 1] * inv);
      }
    }
  }
}

extern "C" void kernel_launch(void* const* d_in, const int* in_sizes, int n_in,
                              void* d_out, int out_size, void* d_ws, size_t ws_size,
                              hipStream_t stream) {
  const float* x  = (const float*)d_in[0];
  const float* Wq = (const float*)d_in[1];
  const float* Wk = (const float*)d_in[2];
  const float* Wv = (const float*)d_in[3];
  const float* Wo = (const float*)d_in[4];
  float* out = (float*)d_out;

  char* ws = (char*)d_ws;
  u16*   Xb    = (u16*)(ws + 0);              // [4096][2048] bf16
  u16*   Wcat  = (u16*)(ws + 16777216);       // [3072][2048] bf16 = {Wq^T, Wk^T, Wv^T}
  u16*   WoT   = (u16*)(ws + 29360128);       // [2048][2048] bf16
  u16*   QKV   = (u16*)(ws + 37748736);       // [4096][3072] bf16 (aliased by AttnB after rope)
  u16*   AttnB = (u16*)(ws + 37748736);       // [4096][2048] bf16
  u16*   Qr    = (u16*)(ws + 88080384);       // [2][32][2048][64] bf16 (exp2-domain scaled)
  u16*   Kr    = (u16*)(ws + 104857600);      // [2][8][2048][64] bf16
  u16*   Vtr   = (u16*)(ws + 109051904);      // [2][8][64][2048] bf16
  float* cosT  = (float*)(ws + 113246208);    // [2048][32]
  float* sinT  = (float*)(ws + 113508352);    // [2048][32]

  float* outK = out + 8388608;
  float* outV = out + 10485760;

  prep_all<<<12544, 256, 0, stream>>>(x, Xb, Wq, Wk, Wv, Wo, Wcat, WoT, cosT, sinT);
  gemm_qkv<<<dim3(12, 16), 512, 0, stream>>>(Xb, Wcat, QKV, Vtr, outV);
  rope_scatter<<<4096, 256, 0, stream>>>(QKV, cosT, sinT, Qr, Kr, outK);
  attn_kernel<<<512, 256, 0, stream>>>(Qr, Kr, Vtr, AttnB);
  gemm128<<<dim3(8, 32), 512, 0, stream>>>(AttnB, WoT, out, 4096, 2048, 2048);
}